// Round 4
// baseline (88.253 us; speedup 1.0000x reference)
//
#include <hip/hip_runtime.h>

// out[row, w] = prod_{w'<=w} cos(x[row, w']),  row = (b,t,h), w in [0,64)
// Each lane owns 16 consecutive wires (4x float4) -> 4 lanes per row.
// Exclusive product-scan across the 4-lane group needs only 3 shuffles per
// wave (covering 1024 wires) vs 5 per 256 wires in the 4-wire/lane version:
// 6.7x less DS-pipe traffic (the R1 kernel was ds_bpermute-throughput-bound).

typedef float f32x4 __attribute__((ext_vector_type(4)));

__global__ __launch_bounds__(256) void quantum_cumprod_cos_kernel(
    const f32x4* __restrict__ x, f32x4* __restrict__ out, int nthreads) {
    const int t = blockIdx.x * blockDim.x + threadIdx.x;
    if (t >= nthreads) return;
    const int sub = t & 3;  // lane position within its 4-lane row group

    // Load 16 wires = 4 consecutive float4 chunks.
    f32x4 v0 = x[t * 4 + 0];
    f32x4 v1 = x[t * 4 + 1];
    f32x4 v2 = x[t * 4 + 2];
    f32x4 v3 = x[t * 4 + 3];

    // cos + local inclusive prefix products over the 16 wires.
    float p[16];
    p[0] = __cosf(v0.x);
    p[1] = p[0] * __cosf(v0.y);
    p[2] = p[1] * __cosf(v0.z);
    p[3] = p[2] * __cosf(v0.w);
    p[4] = p[3] * __cosf(v1.x);
    p[5] = p[4] * __cosf(v1.y);
    p[6] = p[5] * __cosf(v1.z);
    p[7] = p[6] * __cosf(v1.w);
    p[8] = p[7] * __cosf(v2.x);
    p[9] = p[8] * __cosf(v2.y);
    p[10] = p[9] * __cosf(v2.z);
    p[11] = p[10] * __cosf(v2.w);
    p[12] = p[11] * __cosf(v3.x);
    p[13] = p[12] * __cosf(v3.y);
    p[14] = p[13] * __cosf(v3.z);
    p[15] = p[14] * __cosf(v3.w);

    // Exclusive product-scan of the lane totals across the 4-lane group:
    // e = prod of p[15] over lanes with lower sub (1.0 for sub==0).
    const float pl = p[15];
    float e = __shfl_up(pl, 1, 4);
    if (sub == 0) e = 1.0f;
    {
        const float t1 = __shfl_up(e, 1, 4);
        if (sub >= 1) e *= t1;
        const float t2 = __shfl_up(e, 2, 4);
        if (sub >= 2) e *= t2;
    }

    f32x4 o0 = {e * p[0], e * p[1], e * p[2], e * p[3]};
    f32x4 o1 = {e * p[4], e * p[5], e * p[6], e * p[7]};
    f32x4 o2 = {e * p[8], e * p[9], e * p[10], e * p[11]};
    f32x4 o3 = {e * p[12], e * p[13], e * p[14], e * p[15]};
    __builtin_nontemporal_store(o0, &out[t * 4 + 0]);
    __builtin_nontemporal_store(o1, &out[t * 4 + 1]);
    __builtin_nontemporal_store(o2, &out[t * 4 + 2]);
    __builtin_nontemporal_store(o3, &out[t * 4 + 3]);
}

extern "C" void kernel_launch(void* const* d_in, const int* in_sizes, int n_in,
                              void* d_out, int out_size, void* d_ws, size_t ws_size,
                              hipStream_t stream) {
    (void)d_ws; (void)ws_size; (void)n_in;
    const f32x4* x = (const f32x4*)d_in[0];  // (8,4096,1024) fp32
    // d_in[1] (circuit_params) drops out analytically — unused.
    f32x4* out = (f32x4*)d_out;              // (8,4096,1024) fp32

    const int nthreads = out_size / 16;      // 16 wires per thread = 2,097,152
    const int threads = 256;
    const int blocks = (nthreads + threads - 1) / threads;  // 8192, one-shot

    quantum_cumprod_cos_kernel<<<blocks, threads, 0, stream>>>(x, out, nthreads);
}

// Round 5
// 46.672 us; speedup vs baseline: 1.8909x; 1.8909x over previous
//
#include <hip/hip_runtime.h>

// out[row, w] = prod_{w'<=w} cos(x[row, w']),  row = (b,t,h), w in [0,64)
// R1 layout: 16 lanes per 64-wire row, 4 consecutive wires per lane (float4),
// per-instruction addresses contiguous across lanes (16 B/lane, full lines).
// New in R5: 4-way batch unroll — 4 independent chunks in flight per thread
// (4 loads issued together, 4 shuffle-scans interleaved) to hide memory and
// DS latency. No nt stores (neutral when contiguous, harmful when strided).

typedef float f32x4 __attribute__((ext_vector_type(4)));

__global__ __launch_bounds__(256) void quantum_cumprod_cos_kernel(
    const f32x4* __restrict__ x, f32x4* __restrict__ out, int nchunks) {
    const int tid    = blockIdx.x * blockDim.x + threadIdx.x;
    const int stride = gridDim.x * blockDim.x;  // multiple of 16
    const int sub    = tid & 15;  // chunk position in row; invariant across
                                  // unroll members since stride % 16 == 0

    int i = tid;
    // Main: 4 independent chunks per iteration (ILP on loads + DS scan).
    for (; i + 3 * stride < nchunks; i += 4 * stride) {
        float p0[4], p1[4], p2[4], p3[4];
#pragma unroll
        for (int k = 0; k < 4; ++k) {
            const f32x4 v = x[i + k * stride];
            p0[k] = __cosf(v.x);
            p1[k] = p0[k] * __cosf(v.y);
            p2[k] = p1[k] * __cosf(v.z);
            p3[k] = p2[k] * __cosf(v.w);
        }

        // Exclusive product-scan across each 16-lane group, 4 chunks
        // interleaved so the 5 dependent DS steps overlap across chunks.
        float e[4];
#pragma unroll
        for (int k = 0; k < 4; ++k) {
            e[k] = __shfl_up(p3[k], 1, 16);
            if (sub == 0) e[k] = 1.0f;
        }
#pragma unroll
        for (int d = 1; d < 16; d <<= 1) {
#pragma unroll
            for (int k = 0; k < 4; ++k) {
                const float t = __shfl_up(e[k], d, 16);
                if (sub >= d) e[k] *= t;
            }
        }

#pragma unroll
        for (int k = 0; k < 4; ++k) {
            f32x4 o = {e[k] * p0[k], e[k] * p1[k], e[k] * p2[k], e[k] * p3[k]};
            out[i + k * stride] = o;
        }
    }

    // Tail (not taken for 8.4M chunks / 524288 threads = exactly 16 each).
    for (; i < nchunks; i += stride) {
        const f32x4 v = x[i];
        const float q0 = __cosf(v.x);
        const float q1 = q0 * __cosf(v.y);
        const float q2 = q1 * __cosf(v.z);
        const float q3 = q2 * __cosf(v.w);
        float e = __shfl_up(q3, 1, 16);
        if (sub == 0) e = 1.0f;
#pragma unroll
        for (int d = 1; d < 16; d <<= 1) {
            const float t = __shfl_up(e, d, 16);
            if (sub >= d) e *= t;
        }
        f32x4 o = {e * q0, e * q1, e * q2, e * q3};
        out[i] = o;
    }
}

extern "C" void kernel_launch(void* const* d_in, const int* in_sizes, int n_in,
                              void* d_out, int out_size, void* d_ws, size_t ws_size,
                              hipStream_t stream) {
    (void)d_ws; (void)ws_size; (void)n_in;
    const f32x4* x = (const f32x4*)d_in[0];  // (8,4096,1024) fp32
    // d_in[1] (circuit_params) drops out analytically — unused.
    f32x4* out = (f32x4*)d_out;              // (8,4096,1024) fp32

    const int nchunks = out_size / 4;        // 8,388,608
    const int threads = 256;
    int blocks = (nchunks + threads - 1) / threads;
    if (blocks > 2048) blocks = 2048;        // 524288 threads, 16 chunks each

    quantum_cumprod_cos_kernel<<<blocks, threads, 0, stream>>>(x, out, nchunks);
}

// Round 6
// 45.053 us; speedup vs baseline: 1.9589x; 1.0359x over previous
//
#include <hip/hip_runtime.h>

// out[row, w] = prod_{w'<=w} cos(x[row, w']),  row = (b,t,h), w in [0,64)
// 16 lanes per row, 4 wires per lane (float4), shfl-based product scan.
// Final form = R1 kernel: best measured (45.1 us = 94.5% of the 6.29 TB/s
// streaming-copy ceiling on the mandatory 268 MB of app traffic).
// Tested and rejected: nt stores (neutral), 16 wires/lane (write
// amplification, 131->228 MB), 4x grid-stride ILP unroll (neutral).

typedef float f32x4 __attribute__((ext_vector_type(4)));

__global__ __launch_bounds__(256) void quantum_cumprod_cos_kernel(
    const f32x4* __restrict__ x, f32x4* __restrict__ out, int nchunks) {
    const int tid    = blockIdx.x * blockDim.x + threadIdx.x;
    const int stride = gridDim.x * blockDim.x;  // multiple of 16

    for (int i = tid; i < nchunks; i += stride) {
        const int sub = i & 15;  // position of this 4-wire chunk within its row
                                 // == (lane & 15) since stride % 16 == 0

        const f32x4 v = x[i];
        // cos of the 4 wires in this chunk
        const float c0 = __cosf(v.x);
        const float c1 = __cosf(v.y);
        const float c2 = __cosf(v.z);
        const float c3 = __cosf(v.w);
        // local inclusive prefix products
        const float p0 = c0;
        const float p1 = p0 * c1;
        const float p2 = p1 * c2;
        const float p3 = p2 * c3;

        // exclusive product-scan of p3 across the 16-lane group:
        // e = prod of p3 over lanes with lower sub (1.0 for sub==0)
        float e = __shfl_up(p3, 1, 16);
        if (sub == 0) e = 1.0f;
#pragma unroll
        for (int d = 1; d < 16; d <<= 1) {
            const float t = __shfl_up(e, d, 16);
            if (sub >= d) e *= t;
        }

        f32x4 o;
        o.x = e * p0;
        o.y = e * p1;
        o.z = e * p2;
        o.w = e * p3;
        out[i] = o;
    }
}

extern "C" void kernel_launch(void* const* d_in, const int* in_sizes, int n_in,
                              void* d_out, int out_size, void* d_ws, size_t ws_size,
                              hipStream_t stream) {
    (void)d_ws; (void)ws_size; (void)n_in;
    const f32x4* x = (const f32x4*)d_in[0];  // (8,4096,1024) fp32
    // d_in[1] (circuit_params) drops out analytically — unused.
    f32x4* out = (f32x4*)d_out;              // (8,4096,1024) fp32

    const int nchunks = out_size / 4;          // 8*4096*1024/4 = 8,388,608
    const int threads = 256;
    int blocks = (nchunks + threads - 1) / threads;
    if (blocks > 2048) blocks = 2048;          // 8 blocks/CU, grid-stride the rest

    quantum_cumprod_cos_kernel<<<blocks, threads, 0, stream>>>(x, out, nchunks);
}